// Round 5
// baseline (412.495 us; speedup 1.0000x reference)
//
#include <hip/hip_runtime.h>
#include <stdint.h>

// B=32, L1=L2=512, D=1024, fp32 in/out.
// R5: R4 + (1) conv_split phase-1 widened to 8 elem/thread (16B h/l stores,
// 2 upfront f32x4 loads — R4 showed conv at 36% HBM, 9% VALU: issue-bound),
// (2) norm_write vectorized (f32x4 sim reads, u16x4 A1 stores).
// sim_gemm/gemm_nt2 (dbuf+XCD swizzle) unchanged from R4.
// ws layout (~226.3 MiB peak; harness ws = 512 MiB):
//   [0]       v1t  bf16 [B][D][L1]  (32 MiB)   B-operand for PV GEMMs
//   [32Mi]    v2t  bf16 [B][D][L2]  (32 MiB)
//   [64Mi]    v1h  bf16 [B][L1][D]  (32 MiB)   hi split, k-swizzled
//   [96Mi]    v2h  bf16 [B][L2][D]  (32 MiB)
//   [128Mi]   v1l  bf16 [B][L1][D]  (32 MiB)   lo split, k-swizzled
//   [160Mi]   v2l  bf16 [B][L2][D]  (32 MiB)
//   [192Mi]   sim  fp32 [B][L1][L2] (32 MiB)
//   [64Mi]    A1   bf16 [B][L1][L2] (16 MiB)   aliases v1h (dead after sim)
//   [80Mi]    A2t  bf16 [B][L2][L1] (16 MiB)   aliases v1h (dead after sim)
//   [224Mi]   pmaxR/psumR fp32 [B][8][512] (512 KiB each)
//   [225Mi]   pmaxC/psumC fp32 [B][8][512]
//   [226Mi]   rowmax/rowrs/colmax/colrs fp32 [B][512] (64 KiB each)

#define Bn 32
#define Ln 512
#define Dn 1024

typedef __attribute__((ext_vector_type(4))) float f32x4;
typedef __attribute__((ext_vector_type(4))) unsigned short u16x4;
typedef __attribute__((ext_vector_type(8))) unsigned short u16x8;
typedef __attribute__((ext_vector_type(8))) __bf16 bf16x8;

__device__ __forceinline__ unsigned short f2bf(float f) {  // RNE
  unsigned int u = __float_as_uint(f);
  u += 0x7FFFu + ((u >> 16) & 1u);
  return (unsigned short)(u >> 16);
}

__device__ __forceinline__ void async_cp16(const void* g, void* l) {
  __builtin_amdgcn_global_load_lds(
      (__attribute__((address_space(1))) void*)(g),
      (__attribute__((address_space(3))) void*)(l), 16, 0, 0);
}

// ---- fp32 -> {transposed bf16, hi/lo split bf16 (k-swizzled)} ----
// grid (16 dchunk, 8 lchunk, 64), 256 thr.
// Phase 1: 2 iters x 8 d-elems/thread; 16B u16x8 stores for h/l.
// Swizzle: element (l,d) stored at d ^ (((l>>1)&3)<<3) (XOR elem bits 3..4;
// 8-aligned chunks stay 8-aligned -> 16B stores legal).
__global__ __launch_bounds__(256) void conv_split(
    const float* __restrict__ v1, const float* __restrict__ v2,
    unsigned short* __restrict__ v1t, unsigned short* __restrict__ v2t,
    unsigned short* __restrict__ v1h, unsigned short* __restrict__ v1l,
    unsigned short* __restrict__ v2h, unsigned short* __restrict__ v2l) {
  __shared__ float tile[64][65];
  const int z = blockIdx.z;
  const float* src = (z < Bn) ? v1 : v2;
  unsigned short* dt = (z < Bn) ? v1t : v2t;
  unsigned short* dh = (z < Bn) ? v1h : v2h;
  unsigned short* dl = (z < Bn) ? v1l : v2l;
  const int b = z & 31;
  const int d0 = blockIdx.x << 6;
  const int l0 = blockIdx.y << 6;
  const int tid = threadIdx.x;
  const size_t bo = (size_t)b * Ln * Dn;

  // issue all loads first (4x f32x4 = 32B/iter x 2 iters)
  f32x4 xa[2], xb[2];
#pragma unroll
  for (int it = 0; it < 2; it++) {
    int lin = (it << 8) + tid;
    int l = lin >> 3;
    int d8 = (lin & 7) << 3;
    const float* sp = src + (size_t)(b * Ln + l0 + l) * Dn + d0 + d8;
    xa[it] = *(const f32x4*)sp;
    xb[it] = *(const f32x4*)(sp + 4);
  }
#pragma unroll
  for (int it = 0; it < 2; it++) {
    int lin = (it << 8) + tid;
    int l = lin >> 3;
    int d8 = (lin & 7) << 3;
    float xs[8] = {xa[it][0], xa[it][1], xa[it][2], xa[it][3],
                   xb[it][0], xb[it][1], xb[it][2], xb[it][3]};
    u16x8 h8, lo8;
#pragma unroll
    for (int e = 0; e < 8; e++) {
      tile[l][d8 + e] = xs[e];
      unsigned int u = __float_as_uint(xs[e]);
      h8[e] = (unsigned short)(u >> 16);               // truncation split
      float hf = __uint_as_float(u & 0xFFFF0000u);
      lo8[e] = (unsigned short)(__float_as_uint(xs[e] - hf) >> 16);
    }
    int gl = l0 + l;
    int sd = (d0 + d8) ^ (((gl >> 1) & 3) << 3);       // XOR bits 3..4 of d
    size_t off = bo + (size_t)gl * Dn + sd;
    *(u16x8*)(dh + off) = h8;
    *(u16x8*)(dl + off) = lo8;
  }
  __syncthreads();
#pragma unroll
  for (int it = 0; it < 4; it++) {
    int lin = (it << 8) + tid;
    int d = lin >> 4;
    int l4 = (lin & 15) << 2;
    u16x4 o;
    o[0] = f2bf(tile[l4][d]);     o[1] = f2bf(tile[l4 + 1][d]);
    o[2] = f2bf(tile[l4 + 2][d]); o[3] = f2bf(tile[l4 + 3][d]);
    *(u16x4*)(dt + (size_t)(b * Dn + d0 + d) * Ln + l0 + l4) = o;
  }
}

// ---- sim GEMM: bf16 3-MFMA split, dbuf LDS, fused softmax stats ----
// flat grid 512 (XCD-swizzled), 256 thr, 128x128 tile, BK=32.
__global__ __launch_bounds__(256) void sim_gemm(
    const unsigned short* __restrict__ Ahg, const unsigned short* __restrict__ Alg,
    const unsigned short* __restrict__ Bhg, const unsigned short* __restrict__ Blg,
    float* __restrict__ C, const int* __restrict__ v1m,
    const int* __restrict__ v2m,
    float* __restrict__ pmaxR, float* __restrict__ psumR,
    float* __restrict__ pmaxC, float* __restrict__ psumC) {
  __shared__ unsigned short sAh[2][4096], sAl[2][4096];
  __shared__ unsigned short sBh[2][4096], sBl[2][4096];
  // XCD swizzle: XCD k (bid%8==k) owns logical ids [k*64, k*64+64) = 4 batches
  const int bid = blockIdx.x;
  const int id = ((bid & 7) << 6) + (bid >> 3);
  const int b = id >> 4;
  const int m0 = ((id >> 2) & 3) << 7;
  const int n0 = (id & 3) << 7;
  const int tid = threadIdx.x;
  const int lane = tid & 63;
  const int wave = tid >> 6;
  const int wrow = (wave >> 1) << 6;
  const int wcol = (wave & 1) << 6;
  const int r = lane & 15;
  const int q = lane >> 4;
  const int srow = tid >> 2;
  const int skof = (tid & 3) << 3;
  const size_t bo = (size_t)b * Ln * Dn;
  const unsigned short* gah = Ahg + bo + (size_t)(m0 + srow) * Dn + skof;
  const unsigned short* gal = Alg + bo + (size_t)(m0 + srow) * Dn + skof;
  const unsigned short* gbh = Bhg + bo + (size_t)(n0 + srow) * Dn + skof;
  const unsigned short* gbl = Blg + bo + (size_t)(n0 + srow) * Dn + skof;
  const int ldsw = wave << 9;

#define SIM_STAGE(nb, kk)                                        \
  do {                                                           \
    async_cp16(gah + (kk), &sAh[nb][ldsw]);                      \
    async_cp16(gah + 64 * Dn + (kk), &sAh[nb][2048 + ldsw]);     \
    async_cp16(gal + (kk), &sAl[nb][ldsw]);                      \
    async_cp16(gal + 64 * Dn + (kk), &sAl[nb][2048 + ldsw]);     \
    async_cp16(gbh + (kk), &sBh[nb][ldsw]);                      \
    async_cp16(gbh + 64 * Dn + (kk), &sBh[nb][2048 + ldsw]);     \
    async_cp16(gbl + (kk), &sBl[nb][ldsw]);                      \
    async_cp16(gbl + 64 * Dn + (kk), &sBl[nb][2048 + ldsw]);     \
  } while (0)

  const f32x4 zero4 = {0.f, 0.f, 0.f, 0.f};
  f32x4 acc[4][4];
#pragma unroll
  for (int i = 0; i < 4; i++)
#pragma unroll
    for (int j = 0; j < 4; j++) acc[i][j] = zero4;

  SIM_STAGE(0, 0);           // prologue
  __syncthreads();           // drain prologue (vmcnt(0) + barrier)

  int cb = 0;
  for (int k0 = 0; k0 < Dn; k0 += 32, cb ^= 1) {
    if (k0 + 32 < Dn) SIM_STAGE(cb ^ 1, k0 + 32);  // prefetch next tile
    bf16x8 ah[4], al[4], bh[4], bl[4];
#pragma unroll
    for (int t = 0; t < 4; t++) {
      int ra = wrow + (t << 4) + r;
      int sa = (ra << 5) + ((q ^ ((ra >> 1) & 3)) << 3);
      ah[t] = *(const bf16x8*)(&sAh[cb][sa]);
      al[t] = *(const bf16x8*)(&sAl[cb][sa]);
      int rb = wcol + (t << 4) + r;
      int sb = (rb << 5) + ((q ^ ((rb >> 1) & 3)) << 3);
      bh[t] = *(const bf16x8*)(&sBh[cb][sb]);
      bl[t] = *(const bf16x8*)(&sBl[cb][sb]);
    }
#pragma unroll
    for (int tm = 0; tm < 4; tm++)
#pragma unroll
      for (int tn = 0; tn < 4; tn++) {
        acc[tm][tn] = __builtin_amdgcn_mfma_f32_16x16x32_bf16(
            ah[tm], bh[tn], acc[tm][tn], 0, 0, 0);
        acc[tm][tn] = __builtin_amdgcn_mfma_f32_16x16x32_bf16(
            ah[tm], bl[tn], acc[tm][tn], 0, 0, 0);
        acc[tm][tn] = __builtin_amdgcn_mfma_f32_16x16x32_bf16(
            al[tm], bh[tn], acc[tm][tn], 0, 0, 0);
      }
    __syncthreads();         // drains next-tile stage; joins waves
  }
#undef SIM_STAGE

  // C write (fragment layout: col = lane&15, row = (lane>>4)*4 + reg)
  float* Cb = C + (size_t)b * Ln * Ln;
#pragma unroll
  for (int tm = 0; tm < 4; tm++) {
    int rowb = m0 + wrow + (tm << 4) + (q << 2);
#pragma unroll
    for (int reg = 0; reg < 4; reg++) {
      int row = rowb + reg;
#pragma unroll
      for (int tn = 0; tn < 4; tn++) {
        int col = n0 + wcol + (tn << 4) + r;
        Cb[(size_t)row * Ln + col] = acc[tm][tn][reg];
      }
    }
  }

  // ---- fused softmax partial stats ----
  const int* mkr = v1m + (b << 9);
  const int* mkc = v2m + (b << 9);
  const float NEGINF = -__builtin_inff();
  unsigned cmb = 0;  // column (j) masks for this lane's 4 cols
#pragma unroll
  for (int tn = 0; tn < 4; tn++)
    cmb |= (mkc[n0 + wcol + (tn << 4) + r] ? 1u : 0u) << tn;
  unsigned rmb = 0;  // row (i) masks for this lane's 16 rows
#pragma unroll
  for (int t2 = 0; t2 < 16; t2++)
    rmb |= (mkr[m0 + wrow + ((t2 >> 2) << 4) + (q << 2) + (t2 & 3)] ? 1u : 0u)
           << t2;

  // row partials (softmax over j): reduce over r (lane bits 0..3) and tn
  const int nsub = (n0 + wcol) >> 6;
#pragma unroll
  for (int tm = 0; tm < 4; tm++) {
#pragma unroll
    for (int reg = 0; reg < 4; reg++) {
      float m = NEGINF;
#pragma unroll
      for (int tn = 0; tn < 4; tn++)
        if (!((cmb >> tn) & 1)) m = fmaxf(m, acc[tm][tn][reg]);
#pragma unroll
      for (int off = 1; off < 16; off <<= 1)
        m = fmaxf(m, __shfl_xor(m, off));
      float s = 0.f;
#pragma unroll
      for (int tn = 0; tn < 4; tn++)
        if (!((cmb >> tn) & 1)) s += __expf(acc[tm][tn][reg] - m);
#pragma unroll
      for (int off = 1; off < 16; off <<= 1) s += __shfl_xor(s, off);
      if (r == 0) {
        int row = m0 + wrow + (tm << 4) + (q << 2) + reg;
        int idx = (((b << 3) + nsub) << 9) + row;
        pmaxR[idx] = m;
        psumR[idx] = s;
      }
    }
  }

  // col partials (softmax over i): reduce over tm,reg then q (lane bits 4..5)
  const int msub = (m0 + wrow) >> 6;
#pragma unroll
  for (int tn = 0; tn < 4; tn++) {
    float m = NEGINF;
#pragma unroll
    for (int tm = 0; tm < 4; tm++)
#pragma unroll
      for (int reg = 0; reg < 4; reg++)
        if (!((rmb >> ((tm << 2) + reg)) & 1))
          m = fmaxf(m, acc[tm][tn][reg]);
    m = fmaxf(m, __shfl_xor(m, 16));
    m = fmaxf(m, __shfl_xor(m, 32));
    float s = 0.f;
#pragma unroll
    for (int tm = 0; tm < 4; tm++)
#pragma unroll
      for (int reg = 0; reg < 4; reg++)
        if (!((rmb >> ((tm << 2) + reg)) & 1))
          s += __expf(acc[tm][tn][reg] - m);
    s += __shfl_xor(s, 16);
    s += __shfl_xor(s, 32);
    if (q == 0) {
      int col = n0 + wcol + (tn << 4) + r;
      int idx = (((b << 3) + msub) << 9) + col;
      pmaxC[idx] = m;
      psumC[idx] = s;
    }
  }
}

// ---- combine 8 partials per row and per column ----
// grid (128), 256 thr: ids 0..16383 = rows, 16384..32767 = cols.
__global__ __launch_bounds__(256) void comb(
    const float* __restrict__ pmaxR, const float* __restrict__ psumR,
    const float* __restrict__ pmaxC, const float* __restrict__ psumC,
    float* __restrict__ rowmax, float* __restrict__ rowrs,
    float* __restrict__ colmax, float* __restrict__ colrs) {
  const int id = (blockIdx.x << 8) + threadIdx.x;
  const int side = id >> 14;
  const int x = id & 16383;
  const float* pm = side ? pmaxC : pmaxR;
  const float* ps = side ? psumC : psumR;
  const int bq = x >> 9;
  const int j = x & 511;
  const float NEGINF = -__builtin_inff();
  float mm[8], sv[8];
#pragma unroll
  for (int p = 0; p < 8; p++) {
    int idx = (((bq << 3) + p) << 9) + j;
    mm[p] = pm[idx];
    sv[p] = ps[idx];
  }
  float M = NEGINF;
#pragma unroll
  for (int p = 0; p < 8; p++) M = fmaxf(M, mm[p]);
  float S = 0.f;
#pragma unroll
  for (int p = 0; p < 8; p++)
    S += (mm[p] > NEGINF) ? sv[p] * __expf(mm[p] - M) : 0.f;
  float rs = 1.f / S;
  if (side) { colmax[x] = M; colrs[x] = rs; }
  else      { rowmax[x] = M; rowrs[x] = rs; }
}

// ---- fused normalize: one read of sim -> A1 (row sm) + A2t (col sm, T) ----
// grid (8 jc, 8 ic, 32 b), 256 thr.  f32x4 reads, u16x4 A1 stores.
__global__ __launch_bounds__(256) void norm_write(
    const float* __restrict__ sim, const int* __restrict__ v1m,
    const int* __restrict__ v2m,
    const float* __restrict__ rowmax, const float* __restrict__ rowrs,
    const float* __restrict__ colmax, const float* __restrict__ colrs,
    unsigned short* __restrict__ A1, unsigned short* __restrict__ A2t) {
  __shared__ unsigned short Tc[64][66];
  __shared__ float rm[64], rr[64], cmx[64], crx[64];
  __shared__ int jmk[64], imk[64];
  const int b = blockIdx.z;
  const int i0 = blockIdx.y << 6;
  const int j0 = blockIdx.x << 6;
  const int tid = threadIdx.x;
  if (tid < 64) {
    cmx[tid] = colmax[(b << 9) + j0 + tid];
    crx[tid] = colrs[(b << 9) + j0 + tid];
  } else if (tid < 128) {
    int t = tid - 64;
    rm[t] = rowmax[(b << 9) + i0 + t];
    rr[t] = rowrs[(b << 9) + i0 + t];
  } else if (tid < 192) {
    jmk[tid - 128] = v2m[(b << 9) + j0 + tid - 128];
  } else {
    imk[tid - 192] = v1m[(b << 9) + i0 + tid - 192];
  }
  __syncthreads();
  const int ri = tid >> 4;          // 0..15
  const int jj = (tid & 15) << 2;   // 0,4,...,60
  const float* Sb = sim + (size_t)b * (Ln * Ln);
  unsigned short* A1b = A1 + ((size_t)((b << 9) + i0)) * Ln + j0;
#pragma unroll
  for (int p = 0; p < 4; p++) {
    int il = (p << 4) + ri;
    f32x4 x = *(const f32x4*)(Sb + (size_t)(i0 + il) * Ln + j0 + jj);
    float rmv = rm[il], rrv = rr[il];
    int mrow = imk[il];
    u16x4 o1;
#pragma unroll
    for (int e = 0; e < 4; e++) {
      float e1 = jmk[jj + e] ? 0.f : __expf(x[e] - rmv) * rrv;
      o1[e] = f2bf(e1);
      float e2 = mrow ? 0.f : __expf(x[e] - cmx[jj + e]) * crx[jj + e];
      Tc[jj + e][il] = f2bf(e2);
    }
    *(u16x4*)(A1b + (size_t)il * Ln + jj) = o1;
  }
  __syncthreads();
  unsigned short* o = A2t + ((size_t)((b << 9) + j0)) * Ln + i0;
#pragma unroll
  for (int t = 0; t < 4; t++) {
    int c = (t << 8) + tid;
    int j = c >> 4;
    int ch = c & 15;
    u16x4 v;
    v[0] = Tc[j][(ch << 2)];     v[1] = Tc[j][(ch << 2) + 1];
    v[2] = Tc[j][(ch << 2) + 2]; v[3] = Tc[j][(ch << 2) + 3];
    *(u16x4*)(o + (size_t)j * Ln + (ch << 2)) = v;
  }
}

// ---- both PV GEMMs, dbuf + XCD swizzle: flat grid 2048 ----
// NT bf16, M=512 N=1024 K=512, 128x128 tile.
__global__ __launch_bounds__(256) void gemm_nt2(
    const unsigned short* __restrict__ A1g, const unsigned short* __restrict__ A2tg,
    const unsigned short* __restrict__ v2t, const unsigned short* __restrict__ v1t,
    float* __restrict__ out1, float* __restrict__ out2,
    const int* __restrict__ v1m, const int* __restrict__ v2m) {
  const int Mv = 512, Nv = 1024, Kv = 512;
  __shared__ unsigned short As[2][4096];
  __shared__ unsigned short Bs[2][4096];
  const int bid = blockIdx.x;
  const int id = ((bid & 7) << 8) + (bid >> 3);   // XCD chunk swizzle
  const int z = id >> 5;
  const int m0 = ((id >> 3) & 3) << 7;
  const int n0 = (id & 7) << 7;
  const int b = z & 31;
  const int w2 = z >> 5;
  const unsigned short* A = w2 ? A2tg : A1g;
  const unsigned short* Bm = w2 ? v1t : v2t;
  float* C = w2 ? out2 : out1;
  const int* rowmask = w2 ? v2m : v1m;
  const unsigned short* Ab = A + (size_t)b * Mv * Kv;
  const unsigned short* Bb = Bm + (size_t)b * Nv * Kv;
  float* Cb = C + (size_t)b * Mv * Nv;
  const int tid = threadIdx.x;
  const int lane = tid & 63;
  const int wave = tid >> 6;
  const int wrow = (wave >> 1) << 6;
  const int wcol = (wave & 1) << 6;

  const int srow = tid >> 2;
  const int skof = (tid & 3) << 3;
  const unsigned short* ga0 = Ab + (size_t)(m0 + srow) * Kv + skof;
  const unsigned short* ga1 = Ab + (size_t)(m0 + 64 + srow) * Kv + skof;
  const unsigned short* gb0 = Bb + (size_t)(n0 + srow) * Kv + skof;
  const unsigned short* gb1 = Bb + (size_t)(n0 + 64 + srow) * Kv + skof;
  const int ldsw = wave << 9;

#define PV_STAGE(nb, kk)                            \
  do {                                              \
    async_cp16(ga0 + (kk), &As[nb][ldsw]);          \
    async_cp16(ga1 + (kk), &As[nb][2048 + ldsw]);   \
    async_cp16(gb0 + (kk), &Bs[nb][ldsw]);          \
    async_cp16(gb1 + (kk), &Bs[nb][2048 + ldsw]);   \
  } while (0)

  const int r = lane & 15;
  const int q = lane >> 4;

  const f32x4 zero4 = {0.f, 0.f, 0.f, 0.f};
  f32x4 acc[4][4];
#pragma unroll
  for (int i = 0; i < 4; i++)
#pragma unroll
    for (int j = 0; j < 4; j++) acc[i][j] = zero4;

  PV_STAGE(0, 0);
  __syncthreads();

  int cb = 0;
  for (int k0 = 0; k0 < Kv; k0 += 32, cb ^= 1) {
    if (k0 + 32 < Kv) PV_STAGE(cb ^ 1, k0 + 32);
    bf16x8 af[4], bfr[4];
#pragma unroll
    for (int t = 0; t < 4; t++) {
      af[t] = *(const bf16x8*)(&As[cb][((wrow + (t << 4) + r) << 5) + (q << 3)]);
      bfr[t] = *(const bf16x8*)(&Bs[cb][((wcol + (t << 4) + r) << 5) + (q << 3)]);
    }
#pragma unroll
    for (int tm = 0; tm < 4; tm++)
#pragma unroll
      for (int tn = 0; tn < 4; tn++)
        acc[tm][tn] = __builtin_amdgcn_mfma_f32_16x16x32_bf16(
            af[tm], bfr[tn], acc[tm][tn], 0, 0, 0);
    __syncthreads();
  }
#undef PV_STAGE

  const int* mb = rowmask + b * Mv;
#pragma unroll
  for (int tm = 0; tm < 4; tm++) {
    int rowb = m0 + wrow + (tm << 4) + (q << 2);
#pragma unroll
    for (int reg = 0; reg < 4; reg++) {
      int row = rowb + reg;
      float mz = mb[row] ? 0.f : 1.f;
#pragma unroll
      for (int tn = 0; tn < 4; tn++) {
        int col = n0 + wcol + (tn << 4) + r;
        Cb[(size_t)row * Nv + col] = acc[tm][tn][reg] * mz;
      }
    }
  }
}

extern "C" void kernel_launch(void* const* d_in, const int* in_sizes, int n_in,
                              void* d_out, int out_size, void* d_ws,
                              size_t ws_size, hipStream_t stream) {
  (void)in_sizes; (void)n_in; (void)out_size; (void)ws_size;
  const float* v1 = (const float*)d_in[0];
  const float* v2 = (const float*)d_in[1];
  const int* v1m = (const int*)d_in[2];
  const int* v2m = (const int*)d_in[3];
  float* out1 = (float*)d_out;
  float* out2 = out1 + (size_t)Bn * Ln * Dn;

  char* ws = (char*)d_ws;
  const size_t Mi = 1048576;
  unsigned short* v1t = (unsigned short*)(ws);
  unsigned short* v2t = (unsigned short*)(ws + 32 * Mi);
  unsigned short* v1h = (unsigned short*)(ws + 64 * Mi);
  unsigned short* v2h = (unsigned short*)(ws + 96 * Mi);
  unsigned short* v1l = (unsigned short*)(ws + 128 * Mi);
  unsigned short* v2l = (unsigned short*)(ws + 160 * Mi);
  float* sim = (float*)(ws + 192 * Mi);
  unsigned short* A1 = (unsigned short*)(ws + 64 * Mi);    // alias v1h (dead)
  unsigned short* A2t = (unsigned short*)(ws + 80 * Mi);   // alias v1h (dead)
  float* pmaxR = (float*)(ws + 224 * Mi);
  float* psumR = (float*)(ws + 224 * Mi + 512 * 1024);
  float* pmaxC = (float*)(ws + 225 * Mi);
  float* psumC = (float*)(ws + 225 * Mi + 512 * 1024);
  float* rowmax = (float*)(ws + 226 * Mi);
  float* rowrs = (float*)(ws + 226 * Mi + 64 * 1024);
  float* colmax = (float*)(ws + 226 * Mi + 128 * 1024);
  float* colrs = (float*)(ws + 226 * Mi + 192 * 1024);

  dim3 blk(256);
  conv_split<<<dim3(16, 8, 64), blk, 0, stream>>>(v1, v2, v1t, v2t,
                                                  v1h, v1l, v2h, v2l);
  sim_gemm<<<dim3(512), blk, 0, stream>>>(v1h, v1l, v2h, v2l, sim,
                                          v1m, v2m, pmaxR, psumR,
                                          pmaxC, psumC);
  comb<<<dim3(128), blk, 0, stream>>>(pmaxR, psumR, pmaxC, psumC,
                                      rowmax, rowrs, colmax, colrs);
  norm_write<<<dim3(8, 8, 32), blk, 0, stream>>>(sim, v1m, v2m, rowmax, rowrs,
                                                 colmax, colrs, A1, A2t);
  gemm_nt2<<<dim3(2048), blk, 0, stream>>>(A1, A2t, v2t, v1t,
                                           out1, out2, v1m, v2m);
}

// Round 6
// 404.911 us; speedup vs baseline: 1.0187x; 1.0187x over previous
//
#include <hip/hip_runtime.h>
#include <stdint.h>

// B=32, L1=L2=512, D=1024, fp32 in/out.
// R6: conv_split was BW-bound at 5.1 TB/s moving 448 MiB (R5 vectorization
// no-op proved it). Cut bytes: hi/lo split arrays eliminated from global —
// sim_gemm now stages RAW fp32 (same bytes as h+l bf16) with cvt-at-stage,
// 256x256 tile (halves operand re-reads vs 128x128), 8 waves, single-buffer
// 64KB LDS, T14 issue-early/write-late. conv reduced to transpose-cast only
// (read 256 + write 64 MiB). comb: col partials now 4x128-row segments.
// ws layout (~130 MiB peak; harness ws = 512 MiB):
//   [0]       v1t  bf16 [B][D][L1]  (32 MiB)   B-operand for PV GEMMs
//   [32Mi]    v2t  bf16 [B][D][L2]  (32 MiB)
//   [64Mi]    sim  fp32 [B][L1][L2] (32 MiB)
//   [96Mi]    A1   bf16 [B][L1][L2] (16 MiB)
//   [112Mi]   A2t  bf16 [B][L2][L1] (16 MiB)
//   [128Mi]   pmaxR/psumR fp32 [B][8][512] (512 KiB each)
//   [129Mi]   pmaxC/psumC fp32 [B][4][512] (256 KiB each)
//   [129.5Mi] rowmax/rowrs/colmax/colrs fp32 [B][512] (64 KiB each)

#define Bn 32
#define Ln 512
#define Dn 1024

typedef __attribute__((ext_vector_type(4))) float f32x4;
typedef __attribute__((ext_vector_type(4))) unsigned short u16x4;
typedef __attribute__((ext_vector_type(8))) unsigned short u16x8;
typedef __attribute__((ext_vector_type(8))) __bf16 bf16x8;

__device__ __forceinline__ unsigned short f2bf(float f) {  // RNE
  unsigned int u = __float_as_uint(f);
  u += 0x7FFFu + ((u >> 16) & 1u);
  return (unsigned short)(u >> 16);
}

__device__ __forceinline__ void async_cp16(const void* g, void* l) {
  __builtin_amdgcn_global_load_lds(
      (__attribute__((address_space(1))) void*)(g),
      (__attribute__((address_space(3))) void*)(l), 16, 0, 0);
}

// split 8 fp32 -> hi/lo bf16 (truncation split; residual <= 2^-16 * |a|)
__device__ __forceinline__ void split8(f32x4 x0, f32x4 x1,
                                       u16x8* h, u16x8* l) {
  float xs[8] = {x0[0], x0[1], x0[2], x0[3], x1[0], x1[1], x1[2], x1[3]};
  u16x8 hh, ll;
#pragma unroll
  for (int e = 0; e < 8; e++) {
    unsigned int u = __float_as_uint(xs[e]);
    hh[e] = (unsigned short)(u >> 16);
    float hf = __uint_as_float(u & 0xFFFF0000u);
    ll[e] = (unsigned short)(__float_as_uint(xs[e] - hf) >> 16);
  }
  *h = hh;
  *l = ll;
}

// ---- fp32 -> transposed bf16 only: vXt[b][d][l] = bf16(vX[b][l][d]) ----
// grid (16 dchunk, 8 lchunk, 64), 256 thr.  read 256 + write 64 MiB.
__global__ __launch_bounds__(256) void conv_t(
    const float* __restrict__ v1, const float* __restrict__ v2,
    unsigned short* __restrict__ v1t, unsigned short* __restrict__ v2t) {
  __shared__ float tile[64][65];
  const int z = blockIdx.z;
  const float* src = (z < Bn) ? v1 : v2;
  unsigned short* dt = (z < Bn) ? v1t : v2t;
  const int b = z & 31;
  const int d0 = blockIdx.x << 6;
  const int l0 = blockIdx.y << 6;
  const int tid = threadIdx.x;
#pragma unroll
  for (int it = 0; it < 4; it++) {
    int lin = (it << 8) + tid;
    int l = lin >> 4;
    int d4 = (lin & 15) << 2;
    f32x4 x = *(const f32x4*)(src + (size_t)(b * Ln + l0 + l) * Dn + d0 + d4);
    tile[l][d4] = x[0]; tile[l][d4 + 1] = x[1];
    tile[l][d4 + 2] = x[2]; tile[l][d4 + 3] = x[3];
  }
  __syncthreads();
#pragma unroll
  for (int it = 0; it < 4; it++) {
    int lin = (it << 8) + tid;
    int d = lin >> 4;
    int l4 = (lin & 15) << 2;
    u16x4 o;
    o[0] = f2bf(tile[l4][d]);     o[1] = f2bf(tile[l4 + 1][d]);
    o[2] = f2bf(tile[l4 + 2][d]); o[3] = f2bf(tile[l4 + 3][d]);
    *(u16x4*)(dt + (size_t)(b * Dn + d0 + d) * Ln + l0 + l4) = o;
  }
}

// ---- sim GEMM: 256x256 tile, raw fp32 reg-staging + cvt-at-stage ----
// flat grid 128 (XCD-swizzled), 512 thr (8 waves = 2wm x 4wn), BK=32.
// Wave (wm,wn) owns 128x64 output. Single-buffer LDS (64 KB), T14 split:
// issue loads(t+1) -> compute(t) -> barrier -> cvt+ds_write -> barrier.
// Epilogue: fused softmax partials (row: 64-col segs x8; col: 128-row segs x4).
__global__ __launch_bounds__(512) void sim_gemm(
    const float* __restrict__ V1, const float* __restrict__ V2,
    float* __restrict__ C, const int* __restrict__ v1m,
    const int* __restrict__ v2m,
    float* __restrict__ pmaxR, float* __restrict__ psumR,
    float* __restrict__ pmaxC, float* __restrict__ psumC) {
  __shared__ __align__(16) unsigned short sAh[8192], sAl[8192];
  __shared__ __align__(16) unsigned short sBh[8192], sBl[8192];
  // XCD swizzle: 128 blocks, 16 per XCD (= 4 batches x 4 blocks)
  const int bid = blockIdx.x;
  const int id = ((bid & 7) << 4) + (bid >> 3);
  const int b = id >> 2;
  const int m0 = ((id >> 1) & 1) << 8;
  const int n0 = (id & 1) << 8;
  const int tid = threadIdx.x;
  const int lane = tid & 63;
  const int wave = tid >> 6;       // 0..7
  const int wm = wave >> 2;        // 0..1  (128-row half)
  const int wn = wave & 3;         // 0..3  (64-col quarter)
  const int r = lane & 15;
  const int q = lane >> 4;
  // staging: thread covers row srow, 16 consecutive k (2 chunks of 8)
  const int srow = tid >> 1;       // 0..255
  const int sc0 = (tid & 1) << 1;  // chunk base 0 or 2
  const int ss = (srow >> 1) & 3;  // XOR swizzle key
  const size_t bo = (size_t)b * Ln * Dn;
  const float* gA = V1 + bo + (size_t)(m0 + srow) * Dn + (sc0 << 3);
  const float* gB = V2 + bo + (size_t)(n0 + srow) * Dn + (sc0 << 3);
  const int w0 = srow * 32 + ((sc0 ^ ss) << 3);        // elem offsets in LDS
  const int w1 = srow * 32 + (((sc0 + 1) ^ ss) << 3);

  f32x4 xa[4], xb[4];
#define SIM_LOAD(kk)                                             \
  do {                                                           \
    const float* pa = gA + (kk);                                 \
    const float* pb = gB + (kk);                                 \
    xa[0] = *(const f32x4*)pa;       xa[1] = *(const f32x4*)(pa + 4);  \
    xa[2] = *(const f32x4*)(pa + 8); xa[3] = *(const f32x4*)(pa + 12); \
    xb[0] = *(const f32x4*)pb;       xb[1] = *(const f32x4*)(pb + 4);  \
    xb[2] = *(const f32x4*)(pb + 8); xb[3] = *(const f32x4*)(pb + 12); \
  } while (0)
#define SIM_CVTW()                                               \
  do {                                                           \
    u16x8 h_, l_;                                                \
    split8(xa[0], xa[1], &h_, &l_);                              \
    *(u16x8*)(sAh + w0) = h_; *(u16x8*)(sAl + w0) = l_;          \
    split8(xa[2], xa[3], &h_, &l_);                              \
    *(u16x8*)(sAh + w1) = h_; *(u16x8*)(sAl + w1) = l_;          \
    split8(xb[0], xb[1], &h_, &l_);                              \
    *(u16x8*)(sBh + w0) = h_; *(u16x8*)(sBl + w0) = l_;          \
    split8(xb[2], xb[3], &h_, &l_);                              \
    *(u16x8*)(sBh + w1) = h_; *(u16x8*)(sBl + w1) = l_;          \
  } while (0)

  const f32x4 zero4 = {0.f, 0.f, 0.f, 0.f};
  f32x4 acc[8][4];
#pragma unroll
  for (int i = 0; i < 8; i++)
#pragma unroll
    for (int j = 0; j < 4; j++) acc[i][j] = zero4;

  SIM_LOAD(0);
  SIM_CVTW();
  __syncthreads();

  for (int k0 = 0; k0 < Dn; k0 += 32) {
    const bool more = (k0 + 32 < Dn);
    if (more) SIM_LOAD(k0 + 32);   // issue early; consumed after barrier
    bf16x8 bh[4], bl[4];
#pragma unroll
    for (int tn = 0; tn < 4; tn++) {
      int rb = (wn << 6) + (tn << 4) + r;
      int sb = (rb << 5) + ((q ^ ((rb >> 1) & 3)) << 3);
      bh[tn] = *(const bf16x8*)(sBh + sb);
      bl[tn] = *(const bf16x8*)(sBl + sb);
    }
#pragma unroll
    for (int tm = 0; tm < 8; tm++) {
      int ra = (wm << 7) + (tm << 4) + r;
      int sa = (ra << 5) + ((q ^ ((ra >> 1) & 3)) << 3);
      bf16x8 ah = *(const bf16x8*)(sAh + sa);
      bf16x8 al = *(const bf16x8*)(sAl + sa);
#pragma unroll
      for (int tn = 0; tn < 4; tn++) {
        acc[tm][tn] = __builtin_amdgcn_mfma_f32_16x16x32_bf16(
            ah, bh[tn], acc[tm][tn], 0, 0, 0);
        acc[tm][tn] = __builtin_amdgcn_mfma_f32_16x16x32_bf16(
            ah, bl[tn], acc[tm][tn], 0, 0, 0);
        acc[tm][tn] = __builtin_amdgcn_mfma_f32_16x16x32_bf16(
            al, bh[tn], acc[tm][tn], 0, 0, 0);
      }
    }
    __syncthreads();               // all waves done reading this tile
    if (more) SIM_CVTW();          // overwrite LDS with next tile
    __syncthreads();               // writes visible before next compute
  }
#undef SIM_LOAD
#undef SIM_CVTW

  // C write (fragment layout: col = lane&15, row = (lane>>4)*4 + reg)
  float* Cb = C + (size_t)b * Ln * Ln;
#pragma unroll
  for (int tm = 0; tm < 8; tm++) {
    int rowb = m0 + (wm << 7) + (tm << 4) + (q << 2);
#pragma unroll
    for (int reg = 0; reg < 4; reg++) {
      int row = rowb + reg;
#pragma unroll
      for (int tn = 0; tn < 4; tn++) {
        int col = n0 + (wn << 6) + (tn << 4) + r;
        Cb[(size_t)row * Ln + col] = acc[tm][tn][reg];
      }
    }
  }

  // ---- fused softmax partial stats ----
  const int* mkr = v1m + (b << 9);
  const int* mkc = v2m + (b << 9);
  const float NEGINF = -__builtin_inff();
  unsigned cmb = 0;  // this lane's 4 col masks (tn)
#pragma unroll
  for (int tn = 0; tn < 4; tn++)
    cmb |= (mkc[n0 + (wn << 6) + (tn << 4) + r] ? 1u : 0u) << tn;
  unsigned rmb = 0;  // this lane's 32 row masks (tm,reg)
#pragma unroll
  for (int t2 = 0; t2 < 32; t2++)
    rmb |= (mkr[m0 + (wm << 7) + ((t2 >> 2) << 4) + (q << 2) + (t2 & 3)]
                ? 1u : 0u) << t2;

  // row partials (softmax over j): reduce over r-lanes and tn -> 64-col seg
  const int nsub = (n0 >> 6) + wn;  // 0..7
#pragma unroll
  for (int tm = 0; tm < 8; tm++) {
#pragma unroll
    for (int reg = 0; reg < 4; reg++) {
      float m = NEGINF;
#pragma unroll
      for (int tn = 0; tn < 4; tn++)
        if (!((cmb >> tn) & 1)) m = fmaxf(m, acc[tm][tn][reg]);
#pragma unroll
      for (int off = 1; off < 16; off <<= 1)
        m = fmaxf(m, __shfl_xor(m, off));
      float s = 0.f;
#pragma unroll
      for (int tn = 0; tn < 4; tn++)
        if (!((cmb >> tn) & 1)) s += __expf(acc[tm][tn][reg] - m);
#pragma unroll
      for (int off = 1; off < 16; off <<= 1) s += __shfl_xor(s, off);
      if (r == 0) {
        int row = m0 + (wm << 7) + (tm << 4) + (q << 2) + reg;
        int idx = (((b << 3) + nsub) << 9) + row;
        pmaxR[idx] = m;
        psumR[idx] = s;
      }
    }
  }

  // col partials (softmax over i): in-lane over tm,reg then q -> 128-row seg
  const int msub = (m0 >> 7) + wm;  // 0..3
#pragma unroll
  for (int tn = 0; tn < 4; tn++) {
    float m = NEGINF;
#pragma unroll
    for (int tm = 0; tm < 8; tm++)
#pragma unroll
      for (int reg = 0; reg < 4; reg++)
        if (!((rmb >> ((tm << 2) + reg)) & 1))
          m = fmaxf(m, acc[tm][tn][reg]);
    m = fmaxf(m, __shfl_xor(m, 16));
    m = fmaxf(m, __shfl_xor(m, 32));
    float s = 0.f;
#pragma unroll
    for (int tm = 0; tm < 8; tm++)
#pragma unroll
      for (int reg = 0; reg < 4; reg++)
        if (!((rmb >> ((tm << 2) + reg)) & 1))
          s += __expf(acc[tm][tn][reg] - m);
    s += __shfl_xor(s, 16);
    s += __shfl_xor(s, 32);
    if (q == 0) {
      int col = n0 + (wn << 6) + (tn << 4) + r;
      int idx = (((b << 2) + msub) << 9) + col;
      pmaxC[idx] = m;
      psumC[idx] = s;
    }
  }
}

// ---- combine partials: rows have 8 segments, cols have 4 ----
// grid (128), 256 thr: ids 0..16383 = rows, 16384..32767 = cols.
__global__ __launch_bounds__(256) void comb(
    const float* __restrict__ pmaxR, const float* __restrict__ psumR,
    const float* __restrict__ pmaxC, const float* __restrict__ psumC,
    float* __restrict__ rowmax, float* __restrict__ rowrs,
    float* __restrict__ colmax, float* __restrict__ colrs) {
  const int id = (blockIdx.x << 8) + threadIdx.x;
  const int side = id >> 14;
  const int x = id & 16383;
  const int bq = x >> 9;
  const int j = x & 511;
  const float NEGINF = -__builtin_inff();
  if (!side) {
    float mm[8], sv[8];
#pragma unroll
    for (int p = 0; p < 8; p++) {
      int idx = (((bq << 3) + p) << 9) + j;
      mm[p] = pmaxR[idx];
      sv[p] = psumR[idx];
    }
    float M = NEGINF;
#pragma unroll
    for (int p = 0; p < 8; p++) M = fmaxf(M, mm[p]);
    float S = 0.f;
#pragma unroll
    for (int p = 0; p < 8; p++)
      S += (mm[p] > NEGINF) ? sv[p] * __expf(mm[p] - M) : 0.f;
    rowmax[x] = M;
    rowrs[x] = 1.f / S;
  } else {
    float mm[4], sv[4];
#pragma unroll
    for (int p = 0; p < 4; p++) {
      int idx = (((bq << 2) + p) << 9) + j;
      mm[p] = pmaxC[idx];
      sv[p] = psumC[idx];
    }
    float M = NEGINF;
#pragma unroll
    for (int p = 0; p < 4; p++) M = fmaxf(M, mm[p]);
    float S = 0.f;
#pragma unroll
    for (int p = 0; p < 4; p++)
      S += (mm[p] > NEGINF) ? sv[p] * __expf(mm[p] - M) : 0.f;
    colmax[x] = M;
    colrs[x] = 1.f / S;
  }
}

// ---- fused normalize: one read of sim -> A1 (row sm) + A2t (col sm, T) ----
// grid (8 jc, 8 ic, 32 b), 256 thr.  f32x4 reads, u16x4 A1 stores.
__global__ __launch_bounds__(256) void norm_write(
    const float* __restrict__ sim, const int* __restrict__ v1m,
    const int* __restrict__ v2m,
    const float* __restrict__ rowmax, const float* __restrict__ rowrs,
    const float* __restrict__ colmax, const float* __restrict__ colrs,
    unsigned short* __restrict__ A1, unsigned short* __restrict__ A2t) {
  __shared__ unsigned short Tc[64][66];
  __shared__ float rm[64], rr[64], cmx[64], crx[64];
  __shared__ int jmk[64], imk[64];
  const int b = blockIdx.z;
  const int i0 = blockIdx.y << 6;
  const int j0 = blockIdx.x << 6;
  const int tid = threadIdx.x;
  if (tid < 64) {
    cmx[tid] = colmax[(b << 9) + j0 + tid];
    crx[tid] = colrs[(b << 9) + j0 + tid];
  } else if (tid < 128) {
    int t = tid - 64;
    rm[t] = rowmax[(b << 9) + i0 + t];
    rr[t] = rowrs[(b << 9) + i0 + t];
  } else if (tid < 192) {
    jmk[tid - 128] = v2m[(b << 9) + j0 + tid - 128];
  } else {
    imk[tid - 192] = v1m[(b << 9) + i0 + tid - 192];
  }
  __syncthreads();
  const int ri = tid >> 4;          // 0..15
  const int jj = (tid & 15) << 2;   // 0,4,...,60
  const float* Sb = sim + (size_t)b * (Ln * Ln);
  unsigned short* A1b = A1 + ((size_t)((b << 9) + i0)) * Ln + j0;
#pragma unroll
  for (int p = 0; p < 4; p++) {
    int il = (p << 4) + ri;
    f32x4 x = *(const f32x4*)(Sb + (size_t)(i0 + il) * Ln + j0 + jj);
    float rmv = rm[il], rrv = rr[il];
    int mrow = imk[il];
    u16x4 o1;
#pragma unroll
    for (int e = 0; e < 4; e++) {
      float e1 = jmk[jj + e] ? 0.f : __expf(x[e] - rmv) * rrv;
      o1[e] = f2bf(e1);
      float e2 = mrow ? 0.f : __expf(x[e] - cmx[jj + e]) * crx[jj + e];
      Tc[jj + e][il] = f2bf(e2);
    }
    *(u16x4*)(A1b + (size_t)il * Ln + jj) = o1;
  }
  __syncthreads();
  unsigned short* o = A2t + ((size_t)((b << 9) + j0)) * Ln + i0;
#pragma unroll
  for (int t = 0; t < 4; t++) {
    int c = (t << 8) + tid;
    int j = c >> 4;
    int ch = c & 15;
    u16x4 v;
    v[0] = Tc[j][(ch << 2)];     v[1] = Tc[j][(ch << 2) + 1];
    v[2] = Tc[j][(ch << 2) + 2]; v[3] = Tc[j][(ch << 2) + 3];
    *(u16x4*)(o + (size_t)j * Ln + (ch << 2)) = v;
  }
}

// ---- both PV GEMMs, dbuf + XCD swizzle: flat grid 2048 ----
// NT bf16, M=512 N=1024 K=512, 128x128 tile. (unchanged from R4/R5)
__global__ __launch_bounds__(256) void gemm_nt2(
    const unsigned short* __restrict__ A1g, const unsigned short* __restrict__ A2tg,
    const unsigned short* __restrict__ v2t, const unsigned short* __restrict__ v1t,
    float* __restrict__ out1, float* __restrict__ out2,
    const int* __restrict__ v1m, const int* __restrict__ v2m) {
  const int Mv = 512, Nv = 1024, Kv = 512;
  __shared__ unsigned short As[2][4096];
  __shared__ unsigned short Bs[2][4096];
  const int bid = blockIdx.x;
  const int id = ((bid & 7) << 8) + (bid >> 3);   // XCD chunk swizzle
  const int z = id >> 5;
  const int m0 = ((id >> 3) & 3) << 7;
  const int n0 = (id & 7) << 7;
  const int b = z & 31;
  const int w2 = z >> 5;
  const unsigned short* A = w2 ? A2tg : A1g;
  const unsigned short* Bm = w2 ? v1t : v2t;
  float* C = w2 ? out2 : out1;
  const int* rowmask = w2 ? v2m : v1m;
  const unsigned short* Ab = A + (size_t)b * Mv * Kv;
  const unsigned short* Bb = Bm + (size_t)b * Nv * Kv;
  float* Cb = C + (size_t)b * Mv * Nv;
  const int tid = threadIdx.x;
  const int lane = tid & 63;
  const int wave = tid >> 6;
  const int wrow = (wave >> 1) << 6;
  const int wcol = (wave & 1) << 6;

  const int srow = tid >> 2;
  const int skof = (tid & 3) << 3;
  const unsigned short* ga0 = Ab + (size_t)(m0 + srow) * Kv + skof;
  const unsigned short* ga1 = Ab + (size_t)(m0 + 64 + srow) * Kv + skof;
  const unsigned short* gb0 = Bb + (size_t)(n0 + srow) * Kv + skof;
  const unsigned short* gb1 = Bb + (size_t)(n0 + 64 + srow) * Kv + skof;
  const int ldsw = wave << 9;

#define PV_STAGE(nb, kk)                            \
  do {                                              \
    async_cp16(ga0 + (kk), &As[nb][ldsw]);          \
    async_cp16(ga1 + (kk), &As[nb][2048 + ldsw]);   \
    async_cp16(gb0 + (kk), &Bs[nb][ldsw]);          \
    async_cp16(gb1 + (kk), &Bs[nb][2048 + ldsw]);   \
  } while (0)

  const int r = lane & 15;
  const int q = lane >> 4;

  const f32x4 zero4 = {0.f, 0.f, 0.f, 0.f};
  f32x4 acc[4][4];
#pragma unroll
  for (int i = 0; i < 4; i++)
#pragma unroll
    for (int j = 0; j < 4; j++) acc[i][j] = zero4;

  PV_STAGE(0, 0);
  __syncthreads();

  int cb = 0;
  for (int k0 = 0; k0 < Kv; k0 += 32, cb ^= 1) {
    if (k0 + 32 < Kv) PV_STAGE(cb ^ 1, k0 + 32);
    bf16x8 af[4], bfr[4];
#pragma unroll
    for (int t = 0; t < 4; t++) {
      af[t] = *(const bf16x8*)(&As[cb][((wrow + (t << 4) + r) << 5) + (q << 3)]);
      bfr[t] = *(const bf16x8*)(&Bs[cb][((wcol + (t << 4) + r) << 5) + (q << 3)]);
    }
#pragma unroll
    for (int tm = 0; tm < 4; tm++)
#pragma unroll
      for (int tn = 0; tn < 4; tn++)
        acc[tm][tn] = __builtin_amdgcn_mfma_f32_16x16x32_bf16(
            af[tm], bfr[tn], acc[tm][tn], 0, 0, 0);
    __syncthreads();
  }
#undef PV_STAGE

  const int* mb = rowmask + b * Mv;
#pragma unroll
  for (int tm = 0; tm < 4; tm++) {
    int rowb = m0 + wrow + (tm << 4) + (q << 2);
#pragma unroll
    for (int reg = 0; reg < 4; reg++) {
      int row = rowb + reg;
      float mz = mb[row] ? 0.f : 1.f;
#pragma unroll
      for (int tn = 0; tn < 4; tn++) {
        int col = n0 + wcol + (tn << 4) + r;
        Cb[(size_t)row * Nv + col] = acc[tm][tn][reg] * mz;
      }
    }
  }
}

extern "C" void kernel_launch(void* const* d_in, const int* in_sizes, int n_in,
                              void* d_out, int out_size, void* d_ws,
                              size_t ws_size, hipStream_t stream) {
  (void)in_sizes; (void)n_in; (void)out_size; (void)ws_size;
  const float* v1 = (const float*)d_in[0];
  const float* v2 = (const float*)d_in[1];
  const int* v1m = (const int*)d_in[2];
  const int* v2m = (const int*)d_in[3];
  float* out1 = (float*)d_out;
  float* out2 = out1 + (size_t)Bn * Ln * Dn;

  char* ws = (char*)d_ws;
  const size_t Mi = 1048576;
  unsigned short* v1t = (unsigned short*)(ws);
  unsigned short* v2t = (unsigned short*)(ws + 32 * Mi);
  float* sim = (float*)(ws + 64 * Mi);
  unsigned short* A1 = (unsigned short*)(ws + 96 * Mi);
  unsigned short* A2t = (unsigned short*)(ws + 112 * Mi);
  float* pmaxR = (float*)(ws + 128 * Mi);
  float* psumR = (float*)(ws + 128 * Mi + 512 * 1024);
  float* pmaxC = (float*)(ws + 129 * Mi);
  float* psumC = (float*)(ws + 129 * Mi + 256 * 1024);
  float* rowmax = (float*)(ws + 129 * Mi + 512 * 1024);
  float* rowrs = (float*)(ws + 129 * Mi + 576 * 1024);
  float* colmax = (float*)(ws + 129 * Mi + 640 * 1024);
  float* colrs = (float*)(ws + 129 * Mi + 704 * 1024);

  dim3 blk(256);
  conv_t<<<dim3(16, 8, 64), blk, 0, stream>>>(v1, v2, v1t, v2t);
  sim_gemm<<<dim3(128), dim3(512), 0, stream>>>(v1, v2, sim, v1m, v2m,
                                                pmaxR, psumR, pmaxC, psumC);
  comb<<<dim3(128), blk, 0, stream>>>(pmaxR, psumR, pmaxC, psumC,
                                      rowmax, rowrs, colmax, colrs);
  norm_write<<<dim3(8, 8, 32), blk, 0, stream>>>(sim, v1m, v2m, rowmax, rowrs,
                                                 colmax, colrs, A1, A2t);
  gemm_nt2<<<dim3(2048), blk, 0, stream>>>(A1, A2t, v2t, v1t,
                                           out1, out2, v1m, v2m);
}

// Round 7
// 355.116 us; speedup vs baseline: 1.1616x; 1.1402x over previous
//
#include <hip/hip_runtime.h>
#include <stdint.h>

// B=32, L1=L2=512, D=1024, fp32 in/out.
// R7: R6 was right to cvt-at-stage (conv bytes halved) but wrong to run
// 256^2 tiles at grid=128 (half the CUs idle, Occ 10.5%, single-buffer
// serialized cvt). Revert sim to the proven R4 geometry (128^2, grid 512
// XCD-swizzled, 2 blk/CU, dbuf, 1 barrier/step) with reg-staged fp32 +
// RNE split via __bf16 casts (compiler cvt_pk). conv_t launched AFTER
// sim_gemm so its 256MB read hits L3.
// ws layout (~130.3 MiB peak; harness ws = 512 MiB):
//   [0]       v1t  bf16 [B][D][L1]  (32 MiB)   B-operand for PV GEMMs
//   [32Mi]    v2t  bf16 [B][D][L2]  (32 MiB)
//   [64Mi]    sim  fp32 [B][L1][L2] (32 MiB)
//   [96Mi]    A1   bf16 [B][L1][L2] (16 MiB)
//   [112Mi]   A2t  bf16 [B][L2][L1] (16 MiB)
//   [128Mi]   pmaxR/psumR fp32 [B][8][512] (512 KiB each)
//   [129Mi]   pmaxC/psumC fp32 [B][8][512] (512 KiB each)
//   [130Mi]   rowmax/rowrs/colmax/colrs fp32 [B][512] (64 KiB each)

#define Bn 32
#define Ln 512
#define Dn 1024

typedef __attribute__((ext_vector_type(4))) float f32x4;
typedef __attribute__((ext_vector_type(4))) unsigned short u16x4;
typedef __attribute__((ext_vector_type(8))) unsigned short u16x8;
typedef __attribute__((ext_vector_type(8))) __bf16 bf16x8;

__device__ __forceinline__ unsigned short f2bf(float f) {  // RNE
  unsigned int u = __float_as_uint(f);
  u += 0x7FFFu + ((u >> 16) & 1u);
  return (unsigned short)(u >> 16);
}

__device__ __forceinline__ void async_cp16(const void* g, void* l) {
  __builtin_amdgcn_global_load_lds(
      (__attribute__((address_space(1))) void*)(g),
      (__attribute__((address_space(3))) void*)(l), 16, 0, 0);
}

// RNE hi/lo split: hi = rne_bf16(x), lo = rne_bf16(x - hi). Compiler emits
// v_cvt_pk_bf16_f32 for cast pairs (~3 VALU/elem vs ~6 manual trunc).
__device__ __forceinline__ void split8(f32x4 x0, f32x4 x1,
                                       u16x8* h, u16x8* l) {
  float xs[8] = {x0[0], x0[1], x0[2], x0[3], x1[0], x1[1], x1[2], x1[3]};
  u16x8 hh, ll;
#pragma unroll
  for (int e = 0; e < 8; e++) {
    union { __bf16 b; unsigned short u; } hc, lc;
    hc.b = (__bf16)xs[e];
    float hf = (float)hc.b;
    lc.b = (__bf16)(xs[e] - hf);
    hh[e] = hc.u;
    ll[e] = lc.u;
  }
  *h = hh;
  *l = ll;
}

// ---- fp32 -> transposed bf16 only: vXt[b][d][l] = bf16(vX[b][l][d]) ----
// grid (16 dchunk, 8 lchunk, 64), 256 thr.  Runs after sim_gemm: L3-warm.
__global__ __launch_bounds__(256) void conv_t(
    const float* __restrict__ v1, const float* __restrict__ v2,
    unsigned short* __restrict__ v1t, unsigned short* __restrict__ v2t) {
  __shared__ float tile[64][65];
  const int z = blockIdx.z;
  const float* src = (z < Bn) ? v1 : v2;
  unsigned short* dt = (z < Bn) ? v1t : v2t;
  const int b = z & 31;
  const int d0 = blockIdx.x << 6;
  const int l0 = blockIdx.y << 6;
  const int tid = threadIdx.x;
#pragma unroll
  for (int it = 0; it < 4; it++) {
    int lin = (it << 8) + tid;
    int l = lin >> 4;
    int d4 = (lin & 15) << 2;
    f32x4 x = *(const f32x4*)(src + (size_t)(b * Ln + l0 + l) * Dn + d0 + d4);
    tile[l][d4] = x[0]; tile[l][d4 + 1] = x[1];
    tile[l][d4 + 2] = x[2]; tile[l][d4 + 3] = x[3];
  }
  __syncthreads();
#pragma unroll
  for (int it = 0; it < 4; it++) {
    int lin = (it << 8) + tid;
    int d = lin >> 4;
    int l4 = (lin & 15) << 2;
    u16x4 o;
    o[0] = f2bf(tile[l4][d]);     o[1] = f2bf(tile[l4 + 1][d]);
    o[2] = f2bf(tile[l4 + 2][d]); o[3] = f2bf(tile[l4 + 3][d]);
    *(u16x4*)(dt + (size_t)(b * Dn + d0 + d) * Ln + l0 + l4) = o;
  }
}

// ---- sim GEMM: 128x128 tile, reg-staged fp32 + cvt-at-stage, dbuf ----
// flat grid 512 (XCD-swizzled), 256 thr (4 waves), BK=32, 1 barrier/step.
// Per step: issue loads(t+1) -> compute(t) from buf[cb] -> cvt+write(t+1)
// into buf[cb^1] -> barrier.  Fused softmax partial stats in epilogue.
__global__ __launch_bounds__(256) void sim_gemm(
    const float* __restrict__ V1, const float* __restrict__ V2,
    float* __restrict__ C, const int* __restrict__ v1m,
    const int* __restrict__ v2m,
    float* __restrict__ pmaxR, float* __restrict__ psumR,
    float* __restrict__ pmaxC, float* __restrict__ psumC) {
  __shared__ __align__(16) unsigned short sAh[2][4096], sAl[2][4096];
  __shared__ __align__(16) unsigned short sBh[2][4096], sBl[2][4096];
  // XCD swizzle: XCD k (bid%8==k) owns logical ids [k*64, k*64+64) = 4 batches
  const int bid = blockIdx.x;
  const int id = ((bid & 7) << 6) + (bid >> 3);
  const int b = id >> 4;
  const int m0 = ((id >> 2) & 3) << 7;
  const int n0 = (id & 3) << 7;
  const int tid = threadIdx.x;
  const int lane = tid & 63;
  const int wave = tid >> 6;
  const int wrow = (wave >> 1) << 6;
  const int wcol = (wave & 1) << 6;
  const int r = lane & 15;
  const int q = lane >> 4;
  // staging: thread covers row srow, 16 consecutive k (2 chunks of 8)
  const int srow = tid >> 1;        // 0..127
  const int c0 = (tid & 1) << 1;    // chunk base 0 or 2
  const int ss = (srow >> 1) & 3;   // XOR swizzle key (matches read side)
  const size_t bo = (size_t)b * Ln * Dn;
  const float* gA = V1 + bo + (size_t)(m0 + srow) * Dn + (c0 << 3);
  const float* gB = V2 + bo + (size_t)(n0 + srow) * Dn + (c0 << 3);
  const int w0 = (srow << 5) + (((c0    ) ^ ss) << 3);  // elem offset in LDS
  const int w1 = (srow << 5) + (((c0 + 1) ^ ss) << 3);

  f32x4 xa[4], xb[4];
#define SIM_LOAD(kk)                                                   \
  do {                                                                 \
    const float* pa = gA + (kk);                                       \
    const float* pb = gB + (kk);                                       \
    xa[0] = *(const f32x4*)pa;       xa[1] = *(const f32x4*)(pa + 4);  \
    xa[2] = *(const f32x4*)(pa + 8); xa[3] = *(const f32x4*)(pa + 12); \
    xb[0] = *(const f32x4*)pb;       xb[1] = *(const f32x4*)(pb + 4);  \
    xb[2] = *(const f32x4*)(pb + 8); xb[3] = *(const f32x4*)(pb + 12); \
  } while (0)
#define SIM_CVTW(nb)                                                   \
  do {                                                                 \
    u16x8 h_, l_;                                                      \
    split8(xa[0], xa[1], &h_, &l_);                                    \
    *(u16x8*)(&sAh[nb][w0]) = h_; *(u16x8*)(&sAl[nb][w0]) = l_;        \
    split8(xa[2], xa[3], &h_, &l_);                                    \
    *(u16x8*)(&sAh[nb][w1]) = h_; *(u16x8*)(&sAl[nb][w1]) = l_;        \
    split8(xb[0], xb[1], &h_, &l_);                                    \
    *(u16x8*)(&sBh[nb][w0]) = h_; *(u16x8*)(&sBl[nb][w0]) = l_;        \
    split8(xb[2], xb[3], &h_, &l_);                                    \
    *(u16x8*)(&sBh[nb][w1]) = h_; *(u16x8*)(&sBl[nb][w1]) = l_;        \
  } while (0)

  const f32x4 zero4 = {0.f, 0.f, 0.f, 0.f};
  f32x4 acc[4][4];
#pragma unroll
  for (int i = 0; i < 4; i++)
#pragma unroll
    for (int j = 0; j < 4; j++) acc[i][j] = zero4;

  SIM_LOAD(0);
  SIM_CVTW(0);
  __syncthreads();

  int cb = 0;
  for (int k0 = 0; k0 < Dn; k0 += 32, cb ^= 1) {
    const bool more = (k0 + 32 < Dn);
    if (more) SIM_LOAD(k0 + 32);   // issue early; consumed after compute
    bf16x8 bh[4], bl[4];
#pragma unroll
    for (int tn = 0; tn < 4; tn++) {
      int rb = wcol + (tn << 4) + r;
      int sb = (rb << 5) + ((q ^ ((rb >> 1) & 3)) << 3);
      bh[tn] = *(const bf16x8*)(&sBh[cb][sb]);
      bl[tn] = *(const bf16x8*)(&sBl[cb][sb]);
    }
#pragma unroll
    for (int tm = 0; tm < 4; tm++) {
      int ra = wrow + (tm << 4) + r;
      int sa = (ra << 5) + ((q ^ ((ra >> 1) & 3)) << 3);
      bf16x8 ah = *(const bf16x8*)(&sAh[cb][sa]);
      bf16x8 al = *(const bf16x8*)(&sAl[cb][sa]);
#pragma unroll
      for (int tn = 0; tn < 4; tn++) {
        acc[tm][tn] = __builtin_amdgcn_mfma_f32_16x16x32_bf16(
            ah, bh[tn], acc[tm][tn], 0, 0, 0);
        acc[tm][tn] = __builtin_amdgcn_mfma_f32_16x16x32_bf16(
            ah, bl[tn], acc[tm][tn], 0, 0, 0);
        acc[tm][tn] = __builtin_amdgcn_mfma_f32_16x16x32_bf16(
            al, bh[tn], acc[tm][tn], 0, 0, 0);
      }
    }
    if (more) SIM_CVTW(cb ^ 1);    // write NEXT tile into idle buffer
    __syncthreads();               // writes visible before next compute
  }
#undef SIM_LOAD
#undef SIM_CVTW

  // C write (fragment layout: col = lane&15, row = (lane>>4)*4 + reg)
  float* Cb = C + (size_t)b * Ln * Ln;
#pragma unroll
  for (int tm = 0; tm < 4; tm++) {
    int rowb = m0 + wrow + (tm << 4) + (q << 2);
#pragma unroll
    for (int reg = 0; reg < 4; reg++) {
      int row = rowb + reg;
#pragma unroll
      for (int tn = 0; tn < 4; tn++) {
        int col = n0 + wcol + (tn << 4) + r;
        Cb[(size_t)row * Ln + col] = acc[tm][tn][reg];
      }
    }
  }

  // ---- fused softmax partial stats ----
  const int* mkr = v1m + (b << 9);
  const int* mkc = v2m + (b << 9);
  const float NEGINF = -__builtin_inff();
  unsigned cmb = 0;  // column (j) masks for this lane's 4 cols
#pragma unroll
  for (int tn = 0; tn < 4; tn++)
    cmb |= (mkc[n0 + wcol + (tn << 4) + r] ? 1u : 0u) << tn;
  unsigned rmb = 0;  // row (i) masks for this lane's 16 rows
#pragma unroll
  for (int t2 = 0; t2 < 16; t2++)
    rmb |= (mkr[m0 + wrow + ((t2 >> 2) << 4) + (q << 2) + (t2 & 3)] ? 1u : 0u)
           << t2;

  // row partials (softmax over j): reduce over r (lane bits 0..3) and tn
  const int nsub = (n0 + wcol) >> 6;
#pragma unroll
  for (int tm = 0; tm < 4; tm++) {
#pragma unroll
    for (int reg = 0; reg < 4; reg++) {
      float m = NEGINF;
#pragma unroll
      for (int tn = 0; tn < 4; tn++)
        if (!((cmb >> tn) & 1)) m = fmaxf(m, acc[tm][tn][reg]);
#pragma unroll
      for (int off = 1; off < 16; off <<= 1)
        m = fmaxf(m, __shfl_xor(m, off));
      float s = 0.f;
#pragma unroll
      for (int tn = 0; tn < 4; tn++)
        if (!((cmb >> tn) & 1)) s += __expf(acc[tm][tn][reg] - m);
#pragma unroll
      for (int off = 1; off < 16; off <<= 1) s += __shfl_xor(s, off);
      if (r == 0) {
        int row = m0 + wrow + (tm << 4) + (q << 2) + reg;
        int idx = (((b << 3) + nsub) << 9) + row;
        pmaxR[idx] = m;
        psumR[idx] = s;
      }
    }
  }

  // col partials (softmax over i): reduce over tm,reg then q (lane bits 4..5)
  const int msub = (m0 + wrow) >> 6;
#pragma unroll
  for (int tn = 0; tn < 4; tn++) {
    float m = NEGINF;
#pragma unroll
    for (int tm = 0; tm < 4; tm++)
#pragma unroll
      for (int reg = 0; reg < 4; reg++)
        if (!((rmb >> ((tm << 2) + reg)) & 1))
          m = fmaxf(m, acc[tm][tn][reg]);
    m = fmaxf(m, __shfl_xor(m, 16));
    m = fmaxf(m, __shfl_xor(m, 32));
    float s = 0.f;
#pragma unroll
    for (int tm = 0; tm < 4; tm++)
#pragma unroll
      for (int reg = 0; reg < 4; reg++)
        if (!((rmb >> ((tm << 2) + reg)) & 1))
          s += __expf(acc[tm][tn][reg] - m);
    s += __shfl_xor(s, 16);
    s += __shfl_xor(s, 32);
    if (q == 0) {
      int col = n0 + wcol + (tn << 4) + r;
      int idx = (((b << 3) + msub) << 9) + col;
      pmaxC[idx] = m;
      psumC[idx] = s;
    }
  }
}

// ---- combine 8 partials per row and per column ----
// grid (128), 256 thr: ids 0..16383 = rows, 16384..32767 = cols.
__global__ __launch_bounds__(256) void comb(
    const float* __restrict__ pmaxR, const float* __restrict__ psumR,
    const float* __restrict__ pmaxC, const float* __restrict__ psumC,
    float* __restrict__ rowmax, float* __restrict__ rowrs,
    float* __restrict__ colmax, float* __restrict__ colrs) {
  const int id = (blockIdx.x << 8) + threadIdx.x;
  const int side = id >> 14;
  const int x = id & 16383;
  const float* pm = side ? pmaxC : pmaxR;
  const float* ps = side ? psumC : psumR;
  const int bq = x >> 9;
  const int j = x & 511;
  const float NEGINF = -__builtin_inff();
  float mm[8], sv[8];
#pragma unroll
  for (int p = 0; p < 8; p++) {
    int idx = (((bq << 3) + p) << 9) + j;
    mm[p] = pm[idx];
    sv[p] = ps[idx];
  }
  float M = NEGINF;
#pragma unroll
  for (int p = 0; p < 8; p++) M = fmaxf(M, mm[p]);
  float S = 0.f;
#pragma unroll
  for (int p = 0; p < 8; p++)
    S += (mm[p] > NEGINF) ? sv[p] * __expf(mm[p] - M) : 0.f;
  float rs = 1.f / S;
  if (side) { colmax[x] = M; colrs[x] = rs; }
  else      { rowmax[x] = M; rowrs[x] = rs; }
}

// ---- fused normalize: one read of sim -> A1 (row sm) + A2t (col sm, T) ----
// grid (8 jc, 8 ic, 32 b), 256 thr.  f32x4 reads, u16x4 A1 stores.
__global__ __launch_bounds__(256) void norm_write(
    const float* __restrict__ sim, const int* __restrict__ v1m,
    const int* __restrict__ v2m,
    const float* __restrict__ rowmax, const float* __restrict__ rowrs,
    const float* __restrict__ colmax, const float* __restrict__ colrs,
    unsigned short* __restrict__ A1, unsigned short* __restrict__ A2t) {
  __shared__ unsigned short Tc[64][66];
  __shared__ float rm[64], rr[64], cmx[64], crx[64];
  __shared__ int jmk[64], imk[64];
  const int b = blockIdx.z;
  const int i0 = blockIdx.y << 6;
  const int j0 = blockIdx.x << 6;
  const int tid = threadIdx.x;
  if (tid < 64) {
    cmx[tid] = colmax[(b << 9) + j0 + tid];
    crx[tid] = colrs[(b << 9) + j0 + tid];
  } else if (tid < 128) {
    int t = tid - 64;
    rm[t] = rowmax[(b << 9) + i0 + t];
    rr[t] = rowrs[(b << 9) + i0 + t];
  } else if (tid < 192) {
    jmk[tid - 128] = v2m[(b << 9) + j0 + tid - 128];
  } else {
    imk[tid - 192] = v1m[(b << 9) + i0 + tid - 192];
  }
  __syncthreads();
  const int ri = tid >> 4;          // 0..15
  const int jj = (tid & 15) << 2;   // 0,4,...,60
  const float* Sb = sim + (size_t)b * (Ln * Ln);
  unsigned short* A1b = A1 + ((size_t)((b << 9) + i0)) * Ln + j0;
#pragma unroll
  for (int p = 0; p < 4; p++) {
    int il = (p << 4) + ri;
    f32x4 x = *(const f32x4*)(Sb + (size_t)(i0 + il) * Ln + j0 + jj);
    float rmv = rm[il], rrv = rr[il];
    int mrow = imk[il];
    u16x4 o1;
#pragma unroll
    for (int e = 0; e < 4; e++) {
      float e1 = jmk[jj + e] ? 0.f : __expf(x[e] - rmv) * rrv;
      o1[e] = f2bf(e1);
      float e2 = mrow ? 0.f : __expf(x[e] - cmx[jj + e]) * crx[jj + e];
      Tc[jj + e][il] = f2bf(e2);
    }
    *(u16x4*)(A1b + (size_t)il * Ln + jj) = o1;
  }
  __syncthreads();
  unsigned short* o = A2t + ((size_t)((b << 9) + j0)) * Ln + i0;
#pragma unroll
  for (int t = 0; t < 4; t++) {
    int c = (t << 8) + tid;
    int j = c >> 4;
    int ch = c & 15;
    u16x4 v;
    v[0] = Tc[j][(ch << 2)];     v[1] = Tc[j][(ch << 2) + 1];
    v[2] = Tc[j][(ch << 2) + 2]; v[3] = Tc[j][(ch << 2) + 3];
    *(u16x4*)(o + (size_t)j * Ln + (ch << 2)) = v;
  }
}

// ---- both PV GEMMs, dbuf + XCD swizzle: flat grid 2048 ----
// NT bf16, M=512 N=1024 K=512, 128x128 tile. (unchanged from R4/R5)
__global__ __launch_bounds__(256) void gemm_nt2(
    const unsigned short* __restrict__ A1g, const unsigned short* __restrict__ A2tg,
    const unsigned short* __restrict__ v2t, const unsigned short* __restrict__ v1t,
    float* __restrict__ out1, float* __restrict__ out2,
    const int* __restrict__ v1m, const int* __restrict__ v2m) {
  const int Mv = 512, Nv = 1024, Kv = 512;
  __shared__ unsigned short As[2][4096];
  __shared__ unsigned short Bs[2][4096];
  const int bid = blockIdx.x;
  const int id = ((bid & 7) << 8) + (bid >> 3);   // XCD chunk swizzle
  const int z = id >> 5;
  const int m0 = ((id >> 3) & 3) << 7;
  const int n0 = (id & 7) << 7;
  const int b = z & 31;
  const int w2 = z >> 5;
  const unsigned short* A = w2 ? A2tg : A1g;
  const unsigned short* Bm = w2 ? v1t : v2t;
  float* C = w2 ? out2 : out1;
  const int* rowmask = w2 ? v2m : v1m;
  const unsigned short* Ab = A + (size_t)b * Mv * Kv;
  const unsigned short* Bb = Bm + (size_t)b * Nv * Kv;
  float* Cb = C + (size_t)b * Mv * Nv;
  const int tid = threadIdx.x;
  const int lane = tid & 63;
  const int wave = tid >> 6;
  const int wrow = (wave >> 1) << 6;
  const int wcol = (wave & 1) << 6;

  const int srow = tid >> 2;
  const int skof = (tid & 3) << 3;
  const unsigned short* ga0 = Ab + (size_t)(m0 + srow) * Kv + skof;
  const unsigned short* ga1 = Ab + (size_t)(m0 + 64 + srow) * Kv + skof;
  const unsigned short* gb0 = Bb + (size_t)(n0 + srow) * Kv + skof;
  const unsigned short* gb1 = Bb + (size_t)(n0 + 64 + srow) * Kv + skof;
  const int ldsw = wave << 9;

#define PV_STAGE(nb, kk)                            \
  do {                                              \
    async_cp16(ga0 + (kk), &As[nb][ldsw]);          \
    async_cp16(ga1 + (kk), &As[nb][2048 + ldsw]);   \
    async_cp16(gb0 + (kk), &Bs[nb][ldsw]);          \
    async_cp16(gb1 + (kk), &Bs[nb][2048 + ldsw]);   \
  } while (0)

  const int r = lane & 15;
  const int q = lane >> 4;

  const f32x4 zero4 = {0.f, 0.f, 0.f, 0.f};
  f32x4 acc[4][4];
#pragma unroll
  for (int i = 0; i < 4; i++)
#pragma unroll
    for (int j = 0; j < 4; j++) acc[i][j] = zero4;

  PV_STAGE(0, 0);
  __syncthreads();

  int cb = 0;
  for (int k0 = 0; k0 < Kv; k0 += 32, cb ^= 1) {
    if (k0 + 32 < Kv) PV_STAGE(cb ^ 1, k0 + 32);
    bf16x8 af[4], bfr[4];
#pragma unroll
    for (int t = 0; t < 4; t++) {
      af[t] = *(const bf16x8*)(&As[cb][((wrow + (t << 4) + r) << 5) + (q << 3)]);
      bfr[t] = *(const bf16x8*)(&Bs[cb][((wcol + (t << 4) + r) << 5) + (q << 3)]);
    }
#pragma unroll
    for (int tm = 0; tm < 4; tm++)
#pragma unroll
      for (int tn = 0; tn < 4; tn++)
        acc[tm][tn] = __builtin_amdgcn_mfma_f32_16x16x32_bf16(
            af[tm], bfr[tn], acc[tm][tn], 0, 0, 0);
    __syncthreads();
  }
#undef PV_STAGE

  const int* mb = rowmask + b * Mv;
#pragma unroll
  for (int tm = 0; tm < 4; tm++) {
    int rowb = m0 + wrow + (tm << 4) + (q << 2);
#pragma unroll
    for (int reg = 0; reg < 4; reg++) {
      int row = rowb + reg;
      float mz = mb[row] ? 0.f : 1.f;
#pragma unroll
      for (int tn = 0; tn < 4; tn++) {
        int col = n0 + wcol + (tn << 4) + r;
        Cb[(size_t)row * Nv + col] = acc[tm][tn][reg] * mz;
      }
    }
  }
}

extern "C" void kernel_launch(void* const* d_in, const int* in_sizes, int n_in,
                              void* d_out, int out_size, void* d_ws,
                              size_t ws_size, hipStream_t stream) {
  (void)in_sizes; (void)n_in; (void)out_size; (void)ws_size;
  const float* v1 = (const float*)d_in[0];
  const float* v2 = (const float*)d_in[1];
  const int* v1m = (const int*)d_in[2];
  const int* v2m = (const int*)d_in[3];
  float* out1 = (float*)d_out;
  float* out2 = out1 + (size_t)Bn * Ln * Dn;

  char* ws = (char*)d_ws;
  const size_t Mi = 1048576;
  unsigned short* v1t = (unsigned short*)(ws);
  unsigned short* v2t = (unsigned short*)(ws + 32 * Mi);
  float* sim = (float*)(ws + 64 * Mi);
  unsigned short* A1 = (unsigned short*)(ws + 96 * Mi);
  unsigned short* A2t = (unsigned short*)(ws + 112 * Mi);
  float* pmaxR = (float*)(ws + 128 * Mi);
  float* psumR = (float*)(ws + 128 * Mi + 512 * 1024);
  float* pmaxC = (float*)(ws + 129 * Mi);
  float* psumC = (float*)(ws + 129 * Mi + 512 * 1024);
  float* rowmax = (float*)(ws + 130 * Mi);
  float* rowrs = (float*)(ws + 130 * Mi + 64 * 1024);
  float* colmax = (float*)(ws + 130 * Mi + 128 * 1024);
  float* colrs = (float*)(ws + 130 * Mi + 192 * 1024);

  dim3 blk(256);
  sim_gemm<<<dim3(512), blk, 0, stream>>>(v1, v2, sim, v1m, v2m,
                                          pmaxR, psumR, pmaxC, psumC);
  conv_t<<<dim3(16, 8, 64), blk, 0, stream>>>(v1, v2, v1t, v2t);
  comb<<<dim3(128), blk, 0, stream>>>(pmaxR, psumR, pmaxC, psumC,
                                      rowmax, rowrs, colmax, colrs);
  norm_write<<<dim3(8, 8, 32), blk, 0, stream>>>(sim, v1m, v2m, rowmax, rowrs,
                                                 colmax, colrs, A1, A2t);
  gemm_nt2<<<dim3(2048), blk, 0, stream>>>(A1, A2t, v2t, v1t,
                                           out1, out2, v1m, v2m);
}